// Round 8
// baseline (3262.990 us; speedup 1.0000x reference)
//
#include <hip/hip_runtime.h>
#include <cfloat>
#include <climits>

#define NPTS   8192
#define SCENT  2048
#define KNEIGH 32
#define BATCH  4
#define DFEAT  64
#define FPS_T  512
#define PPT    16      // points per thread, strided ownership p = t + 512*j
#define NW     8       // waves per block
#define CAP    64      // fallback candidate capacity

// ---------------------------------------------------------------------------
// Kernel 1 (fused): blocks 0..3 run FPS (one per batch); remaining 2048 blocks
// transpose points (B,D,N)->(B,N,D) concurrently on otherwise-idle CUs.
//
// FPS: f32 fast path + exact-f64 fallback (proof as R3..R6: f32 rounding keeps
// relative error << 2e-6, so if no second point has dist32 >= v1*(1-2e-6) the
// f32 argmax IS the f64 argmax; otherwise candidates with dist32 >= that
// threshold provably contain it and are re-scored exactly in f64 vs the full
// centroid history, lexicographic (d, original idx) = numpy argmax tie rule).
// R8 chain: value-only update max -> per-wave LDS atomicMax(u32 fbits) -> B1
// -> 8 broadcast reads + max -> post-hoc winner/tie scan -> B2 -> coords read.
// ---------------------------------------------------------------------------
__global__ __launch_bounds__(FPS_T, 1) void fps_kernel(const float* __restrict__ xyz,
                                                       float* __restrict__ new_xyz,
                                                       const float* __restrict__ pts,
                                                       float* __restrict__ ptsT) {
    __shared__ float hx[SCENT], hy[SCENT], hz[SCENT];   // centroid coord history
    __shared__ __align__(16) unsigned slotV[2][NW];
    __shared__ unsigned flagsN[2][NW];
    __shared__ float wX[2], wY[2], wZ[2];
    __shared__ int   wCnt[2];
    __shared__ int   scand[CAP];
    __shared__ float scandX[CAP], scandY[CAP], scandZ[CAP];
    __shared__ int   scnt;
    __shared__ double sdd[2][NW];
    __shared__ double sfv[NW];
    __shared__ int   sfo[NW];
    __shared__ float tile[32][33];                      // transpose branch

    const int t = threadIdx.x;

    if (blockIdx.x >= BATCH) {
        // ---------------- transpose branch ----------------
        const int bid = blockIdx.x - BATCH;             // 0..2047
        const int bt  = bid >> 9;
        const int rest = bid & 511;
        const int d0 = (rest >> 8) * 32, n0 = (rest & 255) * 32;
        const int tx = t & 31, ty = t >> 5;             // ty 0..15
#pragma unroll
        for (int i = 0; i < 2; ++i)
            tile[ty + 16 * i][tx] =
                pts[(size_t)bt * DFEAT * NPTS + (size_t)(d0 + ty + 16 * i) * NPTS + n0 + tx];
        __syncthreads();
#pragma unroll
        for (int i = 0; i < 2; ++i)
            ptsT[(size_t)bt * NPTS * DFEAT + (size_t)(n0 + ty + 16 * i) * DFEAT + d0 + tx] =
                tile[tx][ty + 16 * i];
        return;
    }

    // ---------------- FPS branch ----------------
    const int b = blockIdx.x;
    const int lane = t & 63, w = t >> 6;
    const float* X = xyz + (size_t)b * NPTS * 3;

    float px[PPT], py[PPT], pz[PPT], dist[PPT];
#pragma unroll
    for (int j = 0; j < PPT; ++j) {
        int p = t + FPS_T * j;
        px[j] = X[3 * p + 0]; py[j] = X[3 * p + 1]; pz[j] = X[3 * p + 2];
        dist[j] = 1e10f;
    }
    if (t < NW) { slotV[0][t] = 0; slotV[1][t] = 0; flagsN[0][t] = 0; flagsN[1][t] = 0; }
    float cx = X[0], cy = X[1], cz = X[2];
    int buf = 0;
    __syncthreads();

#pragma unroll 1
    for (int s = 0; s < SCENT; ++s) {
        if (t == 0) {
            float* o = new_xyz + (size_t)(b * SCENT + s) * 3;
            o[0] = cx; o[1] = cy; o[2] = cz;
            hx[s] = cx; hy[s] = cy; hz[s] = cz;
        }
        // ---- update + value-only per-thread max (8 VALU/pt) ----
        float m = -1.0f;
#pragma unroll
        for (int j = 0; j < PPT; ++j) {
            float dx = px[j] - cx, dy = py[j] - cy, dz = pz[j] - cz;
            float d  = fmaf(dx, dx, fmaf(dy, dy, dz * dz));
            float nd = fminf(dist[j], d);
            dist[j] = nd;
            m = fmaxf(m, nd);
        }
        atomicMax(&slotV[buf][w], __float_as_uint(m));   // per-wave slot (ds_max_u32)
        __syncthreads();                                 // B1
        // ---- global max: 8 broadcast reads + max tree ----
        unsigned gu = slotV[buf][0];
#pragma unroll
        for (int k = 1; k < NW; ++k) gu = max(gu, slotV[buf][k]);
        const float gv  = __uint_as_float(gu);
        const float gth = __fmul_rn(gv, 0.999998f);      // v1*(1-2e-6)
        // ---- post-hoc winner / tie detection ----
        bool q = (m >= gth);                             // thread has >=1 candidate
        unsigned long long qb = __ballot(q);
        if (lane == 0) flagsN[buf][w] = (unsigned)__popcll(qb);
        if (qb) {                                        // wave-uniform skip
            int myCnt = 0; float myX = 0.f, myY = 0.f, myZ = 0.f;
            if (q) {
#pragma unroll
                for (int j = 0; j < PPT; ++j) {
                    bool c = dist[j] >= gth;
                    myCnt += c ? 1 : 0;
                    myX = c ? px[j] : myX;               // static selects: no scratch
                    myY = c ? py[j] : myY;
                    myZ = c ? pz[j] : myZ;
                }
                if (m == gv) {                           // the winner thread (unique in fast path)
                    wX[buf] = myX; wY[buf] = myY; wZ[buf] = myZ;
                    wCnt[buf] = myCnt;
                }
            }
        }
        __syncthreads();                                 // B2
        int sumN = 0;
#pragma unroll
        for (int k = 0; k < NW; ++k) sumN += flagsN[buf][k];

        if (sumN >= 2 || wCnt[buf] >= 2) {
            // ---- exact f64 fallback (block-uniform, rare) ----
            if (t == 0) scnt = 0;
            __syncthreads();
#pragma unroll
            for (int j = 0; j < PPT; ++j) {
                if (dist[j] >= gth) {
                    int slot = atomicAdd(&scnt, 1);
                    if (slot < CAP) {
                        scand[slot]  = t + FPS_T * j;    // original index (no sort)
                        scandX[slot] = px[j]; scandY[slot] = py[j]; scandZ[slot] = pz[j];
                    }
                }
            }
            __syncthreads();
            const int mm = scnt;
            if (mm <= CAP) {
                double bd = -1.0; int bi = INT_MAX; float bx = cx, by = cy, bz = cz;
#pragma unroll 1
                for (int k = 0; k < mm; ++k) {
                    const int pos = scand[k];
                    const double pxd = (double)scandX[k], pyd = (double)scandY[k],
                                 pzd = (double)scandZ[k];
                    double dd = 1e10;
                    for (int i = t; i <= s; i += FPS_T) {
                        double ddx = __dsub_rn(pxd, (double)hx[i]);
                        double ddy = __dsub_rn(pyd, (double)hy[i]);
                        double ddz = __dsub_rn(pzd, (double)hz[i]);
                        double d = __dadd_rn(__dadd_rn(__dmul_rn(ddx, ddx), __dmul_rn(ddy, ddy)),
                                             __dmul_rn(ddz, ddz));
                        dd = fmin(dd, d);
                    }
#pragma unroll
                    for (int off = 32; off >= 1; off >>= 1)
                        dd = fmin(dd, __shfl_down(dd, off));
                    if (lane == 0) sdd[k & 1][w] = dd;
                    __syncthreads();
                    double ddm = sdd[k & 1][0];
#pragma unroll
                    for (int w2 = 1; w2 < NW; ++w2) ddm = fmin(ddm, sdd[k & 1][w2]);
                    if (ddm > bd || (ddm == bd && pos < bi)) {
                        bd = ddm; bi = pos;
                        bx = scandX[k]; by = scandY[k]; bz = scandZ[k];
                    }
                }
                cx = bx; cy = by; cz = bz;               // uniform across threads
            } else {
                // safety net: full exact scan (practically unreachable)
                double bv = -1.0; int bi = INT_MAX;
#pragma unroll 1
                for (int j = 0; j < PPT; ++j) {
                    const double pxd = (double)px[j], pyd = (double)py[j], pzd = (double)pz[j];
                    double dd = 1e10;
                    for (int i = 0; i <= s; ++i) {
                        double ddx = __dsub_rn(pxd, (double)hx[i]);
                        double ddy = __dsub_rn(pyd, (double)hy[i]);
                        double ddz = __dsub_rn(pzd, (double)hz[i]);
                        double d = __dadd_rn(__dadd_rn(__dmul_rn(ddx, ddx), __dmul_rn(ddy, ddy)),
                                             __dmul_rn(ddz, ddz));
                        dd = fmin(dd, d);
                    }
                    int pidx = t + FPS_T * j;
                    if (dd > bv || (dd == bv && pidx < bi)) { bv = dd; bi = pidx; }
                }
#pragma unroll
                for (int off = 32; off >= 1; off >>= 1) {
                    double ov = __shfl_down(bv, off);
                    int    oi = __shfl_down(bi, off);
                    if (ov > bv || (ov == bv && oi < bi)) { bv = ov; bi = oi; }
                }
                if (lane == 0) { sfv[w] = bv; sfo[w] = bi; }
                __syncthreads();
                bv = sfv[0]; bi = sfo[0];
#pragma unroll
                for (int w2 = 1; w2 < NW; ++w2) {
                    double ov = sfv[w2]; int oi = sfo[w2];
                    if (ov > bv || (ov == bv && oi < bi)) { bv = ov; bi = oi; }
                }
                if ((bi & (FPS_T - 1)) == t) {           // owner broadcasts coords
                    float ox = 0.f, oy = 0.f, oz = 0.f;
#pragma unroll
                    for (int j = 0; j < PPT; ++j) {
                        bool c = (bi == t + FPS_T * j);
                        ox = c ? px[j] : ox; oy = c ? py[j] : oy; oz = c ? pz[j] : oz;
                    }
                    wX[buf] = ox; wY[buf] = oy; wZ[buf] = oz;
                }
                __syncthreads();
                cx = wX[buf]; cy = wY[buf]; cz = wZ[buf];
            }
        } else {
            cx = wX[buf]; cy = wY[buf]; cz = wZ[buf];    // provably unique f64 argmax
        }
        if (t < NW) { slotV[buf][t] = 0; flagsN[buf][t] = 0; }   // safe: consumed pre-B2
        buf ^= 1;
    }
}

// ---------------------------------------------------------------------------
// Kernel 3: KNN, one WAVE per query (f64-exact ordering, wave-parallel sorted
// top-32 with ballot/shfl insertion).
// ---------------------------------------------------------------------------
__global__ __launch_bounds__(256) void knn_kernel(const float* __restrict__ xyz,
                                                  const float* __restrict__ new_xyz,
                                                  int* __restrict__ knn_idx) {
    const int b    = blockIdx.y;
    const int wid  = threadIdx.x >> 6;
    const int lane = threadIdx.x & 63;
    const int qi   = blockIdx.x * 4 + wid;

    __shared__ float4 sp[2048];
    __shared__ double sp2[2048];

    const float* q = new_xyz + (size_t)(b * SCENT + qi) * 3;
    const double qx = (double)q[0], qy = (double)q[1], qz = (double)q[2];
    const double q2 = __dadd_rn(__dadd_rn(__dmul_rn(qx, qx), __dmul_rn(qy, qy)),
                                __dmul_rn(qz, qz));

    double ld   = DBL_MAX;
    int    li   = 0x7fffffff;
    double taud = DBL_MAX;
    int    taui = 0x7fffffff;

    const float* Xb = xyz + (size_t)b * NPTS * 3;
#pragma unroll 1
    for (int c = 0; c < 4; ++c) {
        __syncthreads();
#pragma unroll
        for (int r = 0; r < 8; ++r) {
            int pl = r * 256 + threadIdx.x;
            int p  = c * 2048 + pl;
            float x = Xb[3 * p + 0], y = Xb[3 * p + 1], z = Xb[3 * p + 2];
            sp[pl] = make_float4(x, y, z, 0.0f);
            double dx = (double)x, dy = (double)y, dz = (double)z;
            sp2[pl] = __dadd_rn(__dadd_rn(__dmul_rn(dx, dx), __dmul_rn(dy, dy)),
                                __dmul_rn(dz, dz));
        }
        __syncthreads();
#pragma unroll 1
        for (int i = 0; i < 32; ++i) {
            const int pl   = i * 64 + lane;
            const int pidx = c * 2048 + pl;
            float4 P = sp[pl];
            double px = (double)P.x, py = (double)P.y, pz = (double)P.z;
            double qp = __dadd_rn(__dadd_rn(__dmul_rn(qx, px), __dmul_rn(qy, py)),
                                  __dmul_rn(qz, pz));
            double d  = __dsub_rn(__dadd_rn(q2, sp2[pl]), __dmul_rn(2.0, qp));
            bool cand = (d < taud) || (d == taud && pidx < taui);
            unsigned long long m = __ballot(cand);
            while (m) {
                int sl = __ffsll((unsigned long long)m) - 1;
                m &= m - 1;
                double dv = __shfl(d, sl);
                int    iv = __shfl(pidx, sl);
                if (dv < taud || (dv == taud && iv < taui)) {
                    bool gt = (lane < 32) && (ld > dv || (ld == dv && li > iv));
                    unsigned long long gm = __ballot(gt);
                    double ud = __shfl_up(ld, 1);
                    int    ui = __shfl_up(li, 1);
                    if (gt) { ld = ud; li = ui; }
                    bool first = gt && ((lane == 0) || !((gm >> (lane - 1)) & 1ull));
                    if (first) { ld = dv; li = iv; }
                    taud = __shfl(ld, 31);
                    taui = __shfl(li, 31);
                }
            }
        }
    }
    if (lane < 32) knn_idx[(size_t)(b * SCENT + qi) * KNEIGH + lane] = li;
}

// ---------------------------------------------------------------------------
// Kernel 4: gather + 3-layer MLP (BN folded, fp32) + max over K.
// ---------------------------------------------------------------------------
__global__ __launch_bounds__(256) void mlp_kernel(
    const float* __restrict__ xyz, const float* __restrict__ new_xyz,
    const float* __restrict__ ptsT, const int* __restrict__ knn_idx,
    const float* __restrict__ w0, const float* __restrict__ g0,
    const float* __restrict__ b0, const float* __restrict__ m0,
    const float* __restrict__ v0, const float* __restrict__ w1,
    const float* __restrict__ g1, const float* __restrict__ b1,
    const float* __restrict__ m1, const float* __restrict__ v1,
    const float* __restrict__ w2, const float* __restrict__ g2,
    const float* __restrict__ b2, const float* __restrict__ m2,
    const float* __restrict__ v2, float* __restrict__ out_points) {

    __shared__ float regA[8192];
    __shared__ float regB[4096];
    __shared__ float prm[512];

    const int t = threadIdx.x;
    if (t < 64) {
        float a0v = g0[t] / sqrtf(v0[t] + 1e-5f);
        prm[t]       = a0v;
        prm[64 + t]  = b0[t] - m0[t] * a0v;
        float a1v = g1[t] / sqrtf(v1[t] + 1e-5f);
        prm[128 + t] = a1v;
        prm[192 + t] = b1[t] - m1[t] * a1v;
    } else if (t < 192) {
        int o = t - 64;
        float a2v = g2[o] / sqrtf(v2[o] + 1e-5f);
        prm[256 + o] = a2v;
        prm[384 + o] = b2[o] - m2[o] * a2v;
    }
    for (int idx = t; idx < 64 * 68; idx += 256) {
        int o = idx / 68, i = idx - o * 68;
        float v;
        if (i < 64)      v = w0[o * 67 + 3 + i];
        else if (i < 67) v = w0[o * 67 + (i - 64)];
        else             v = 0.0f;
        regA[idx] = v;
    }
    for (int idx = t; idx < 64 * 64; idx += 256) regB[idx] = w1[idx];
    __syncthreads();

    const int gid = blockIdx.x * 256 + t;
    const int sl  = gid >> 5;
    const int s   = sl & (SCENT - 1);
    const int b   = sl >> 11;
    const int nidx = knn_idx[gid];

    const float* q  = new_xyz + (size_t)(b * SCENT + s) * 3;
    const float* P3 = xyz + (size_t)(b * NPTS + nidx) * 3;
    const float dx = P3[0] - q[0], dy = P3[1] - q[1], dz = P3[2] - q[2];

    const float4* F = (const float4*)(ptsT + ((size_t)b * NPTS + nidx) * 64);
    float4 xv[17];
#pragma unroll
    for (int i = 0; i < 16; ++i) xv[i] = F[i];
    xv[16] = make_float4(dx, dy, dz, 0.0f);

    float h0[64];
    const float4* W0 = (const float4*)regA;
#pragma unroll
    for (int o = 0; o < 64; ++o) {
        float acc = 0.f;
#pragma unroll
        for (int i = 0; i < 17; ++i) {
            float4 w = W0[o * 17 + i];
            acc = fmaf(xv[i].x, w.x, acc);
            acc = fmaf(xv[i].y, w.y, acc);
            acc = fmaf(xv[i].z, w.z, acc);
            acc = fmaf(xv[i].w, w.w, acc);
        }
        h0[o] = fmaxf(fmaf(acc, prm[o], prm[64 + o]), 0.f);
    }
    __syncthreads();
    for (int idx = t; idx < 128 * 64; idx += 256) regA[idx] = w2[idx];
    __syncthreads();

    float h1[64];
    const float4* W1 = (const float4*)regB;
#pragma unroll
    for (int o = 0; o < 64; ++o) {
        float acc = 0.f;
#pragma unroll
        for (int i = 0; i < 16; ++i) {
            float4 w = W1[o * 16 + i];
            acc = fmaf(h0[4 * i + 0], w.x, acc);
            acc = fmaf(h0[4 * i + 1], w.y, acc);
            acc = fmaf(h0[4 * i + 2], w.z, acc);
            acc = fmaf(h0[4 * i + 3], w.w, acc);
        }
        h1[o] = fmaxf(fmaf(acc, prm[128 + o], prm[192 + o]), 0.f);
    }

    const float4* W2 = (const float4*)regA;
    float* outp = out_points + (size_t)b * 128 * SCENT + s;
    const int lane = t & 63;
#pragma unroll 1
    for (int o = 0; o < 128; ++o) {
        float acc = 0.f;
#pragma unroll
        for (int i = 0; i < 16; ++i) {
            float4 w = W2[o * 16 + i];
            acc = fmaf(h1[4 * i + 0], w.x, acc);
            acc = fmaf(h1[4 * i + 1], w.y, acc);
            acc = fmaf(h1[4 * i + 2], w.z, acc);
            acc = fmaf(h1[4 * i + 3], w.w, acc);
        }
        float y = fmaxf(fmaf(acc, prm[256 + o], prm[384 + o]), 0.f);
#pragma unroll
        for (int off = 16; off >= 1; off >>= 1) y = fmaxf(y, __shfl_xor(y, off));
        if ((lane & 31) == 0) outp[(size_t)o * SCENT] = y;
    }
}

// ---------------------------------------------------------------------------
extern "C" void kernel_launch(void* const* d_in, const int* in_sizes, int n_in,
                              void* d_out, int out_size, void* d_ws, size_t ws_size,
                              hipStream_t stream) {
    const float* xyz    = (const float*)d_in[0];
    const float* points = (const float*)d_in[1];
    const float* w0 = (const float*)d_in[2];
    const float* g0 = (const float*)d_in[3];
    const float* b0 = (const float*)d_in[4];
    const float* m0 = (const float*)d_in[5];
    const float* v0 = (const float*)d_in[6];
    const float* w1 = (const float*)d_in[7];
    const float* g1 = (const float*)d_in[8];
    const float* b1 = (const float*)d_in[9];
    const float* m1 = (const float*)d_in[10];
    const float* v1 = (const float*)d_in[11];
    const float* w2 = (const float*)d_in[12];
    const float* g2 = (const float*)d_in[13];
    const float* b2 = (const float*)d_in[14];
    const float* m2 = (const float*)d_in[15];
    const float* v2 = (const float*)d_in[16];

    float* out_xyz    = (float*)d_out;                               // (B,S,3)
    float* out_points = (float*)d_out + (size_t)BATCH * SCENT * 3;   // (B,128,S)

    char* ws = (char*)d_ws;
    int*   knn_idx = (int*)(ws + 32768);
    float* ptsT    = (float*)(ws + 32768 + (size_t)BATCH * SCENT * KNEIGH * 4);

    fps_kernel<<<BATCH + 2048, FPS_T, 0, stream>>>(xyz, out_xyz, points, ptsT);
    knn_kernel<<<dim3(SCENT / 4, BATCH), 256, 0, stream>>>(xyz, out_xyz, knn_idx);
    mlp_kernel<<<(BATCH * SCENT * KNEIGH) / 256, 256, 0, stream>>>(
        xyz, out_xyz, ptsT, knn_idx,
        w0, g0, b0, m0, v0, w1, g1, b1, m1, v1, w2, g2, b2, m2, v2, out_points);
}

// Round 9
// 2713.999 us; speedup vs baseline: 1.2023x; 1.2023x over previous
//
#include <hip/hip_runtime.h>
#include <cfloat>
#include <climits>

#define NPTS   8192
#define SCENT  2048
#define KNEIGH 32
#define BATCH  4
#define DFEAT  64
#define FPS_T  512
#define PPT    16      // points per thread, strided ownership p = t + 512*j
#define NW     8       // waves per block
#define CAP    64      // fallback candidate capacity

// DPP max step over uint (positive-f32 bit pattern preserves order).
// old=0 is the identity for non-negative values; invalid/masked lanes give 0.
#define DPPMAX(u, ctrl, rmask)                                                        \
    { unsigned _t = (unsigned)__builtin_amdgcn_update_dpp(0, (int)(u), (ctrl),        \
                                                          (rmask), 0xf, false);      \
      (u) = ((u) > _t) ? (u) : _t; }

// ---------------------------------------------------------------------------
// Kernel 1: FPS. f32 fast path + exact-f64 fallback (proof as R3..R8: f32
// rounding keeps relative error << 2e-6, so if no second point has dist32 >=
// v1*(1-2e-6) the f32 argmax IS the f64 argmax; otherwise candidates with
// dist32 >= that threshold provably contain it and are re-scored exactly in
// f64 vs the centroid history, lexicographic (d, original idx) = numpy rule).
// R9 chain: update (regs) -> DPP wave-max (VALU, no ds_bpermute) -> ballot +
// readlane winner idx -> ds_write_b64 slot -> B1 -> 8 broadcast slot reads +
// umax merge -> coords from LDS point table. ONE barrier; NO global store in
// the loop (new_xyz written once at the end from LDS history).
// ---------------------------------------------------------------------------
__global__ __launch_bounds__(FPS_T, 1) void fps_kernel(const float* __restrict__ xyz,
                                                       float* __restrict__ new_xyz) {
    const int b = blockIdx.x, t = threadIdx.x;
    const int lane = t & 63, w = t >> 6;
    const float* X = xyz + (size_t)b * NPTS * 3;

    __shared__ float sx[NPTS], sy[NPTS], sz[NPTS];   // 96 KB point table
    __shared__ float hx[SCENT], hy[SCENT], hz[SCENT];// 24 KB centroid history
    __shared__ uint2 slots[2][NW];
    __shared__ int   scand[CAP];
    __shared__ int   scnt;
    __shared__ double sdd[2][NW];
    __shared__ double sfv[NW];
    __shared__ int   sfo[NW];

    for (int p = t; p < NPTS; p += FPS_T) {
        sx[p] = X[3 * p + 0]; sy[p] = X[3 * p + 1]; sz[p] = X[3 * p + 2];
    }

    float px[PPT], py[PPT], pz[PPT], dist[PPT];
#pragma unroll
    for (int j = 0; j < PPT; ++j) {
        int p = t + FPS_T * j;
        px[j] = X[3 * p + 0]; py[j] = X[3 * p + 1]; pz[j] = X[3 * p + 2];
        dist[j] = 1e10f;
    }
    float cx = X[0], cy = X[1], cz = X[2];
    int buf = 0;
    __syncthreads();

#pragma unroll 1
    for (int s = 0; s < SCENT; ++s) {
        if (t == 0) { hx[s] = cx; hy[s] = cy; hz[s] = cz; }   // LDS only

        // ---- update + two independent (v,idx) max chains ----
        float ma = -1.f, mb = -1.f; int ia = 0, ib = 0;
#pragma unroll
        for (int j = 0; j < PPT; j += 2) {
            {
                float dx = px[j] - cx, dy = py[j] - cy, dz = pz[j] - cz;
                float d  = fmaf(dx, dx, fmaf(dy, dy, dz * dz));
                float nd = fminf(dist[j], d); dist[j] = nd;
                bool g = nd > ma; ma = g ? nd : ma; ia = g ? (t + FPS_T * j) : ia;
            }
            {
                float dx = px[j+1] - cx, dy = py[j+1] - cy, dz = pz[j+1] - cz;
                float d  = fmaf(dx, dx, fmaf(dy, dy, dz * dz));
                float nd = fminf(dist[j+1], d); dist[j+1] = nd;
                bool g = nd > mb; mb = g ? nd : mb; ib = g ? (t + FPS_T * (j+1)) : ib;
            }
        }
        bool gb = mb > ma;
        float m = gb ? mb : ma;
        int  mi = gb ? ib : ia;

        // ---- wave max via DPP (pure VALU) ----
        unsigned myU = __float_as_uint(m);
        unsigned u = myU;
        DPPMAX(u, 0x111, 0xf);   // row_shr:1
        DPPMAX(u, 0x112, 0xf);   // row_shr:2
        DPPMAX(u, 0x114, 0xf);   // row_shr:4
        DPPMAX(u, 0x118, 0xf);   // row_shr:8
        DPPMAX(u, 0x142, 0xa);   // row_bcast:15
        DPPMAX(u, 0x143, 0xc);   // row_bcast:31
        const unsigned wu = (unsigned)__builtin_amdgcn_readlane((int)u, 63);

        // ---- winner idx + near-tie flags ----
        unsigned long long wb = __ballot(myU == wu);
        const int wl   = __ffsll(wb) - 1;
        const int widx = __builtin_amdgcn_readlane(mi, wl);
        const float thwf = __fmul_rn(__uint_as_float(wu), 0.999998f);
        int cnt = 0;
#pragma unroll
        for (int j = 0; j < PPT; ++j) cnt += (dist[j] >= thwf) ? 1 : 0;
        unsigned long long c1 = __ballot(cnt >= 1);
        unsigned long long c2 = __ballot(cnt >= 2);
        const unsigned tw = (c2 || __popcll(c1) >= 2) ? 1u : 0u;
        if (lane == 0)
            slots[buf][w] = make_uint2(wu, (unsigned)widx | (tw << 14));
        __syncthreads();                                  // the ONE barrier

        // ---- redundant merge: 8 broadcast reads + umax tree ----
        uint2 sv[NW];
#pragma unroll
        for (int k = 0; k < NW; ++k) sv[k] = slots[buf][k];
        unsigned gu = sv[0].x;
#pragma unroll
        for (int k = 1; k < NW; ++k) gu = (sv[k].x > gu) ? sv[k].x : gu;
        const float gvf = __uint_as_float(gu);
        const float gthf = __fmul_rn(gvf, 0.999998f);
        const unsigned ugth = __float_as_uint(gthf);
        int nw = 0;
#pragma unroll
        for (int k = 0; k < NW; ++k) nw += (sv[k].x >= ugth) ? 1 : 0;
        unsigned meta = 0;
#pragma unroll
        for (int k = NW - 1; k >= 0; --k) if (sv[k].x == gu) meta = sv[k].y;
        const int wtie = (meta >> 14) & 1;
        int i1 = (int)(meta & 0x3fffu);

        if (nw >= 2 || wtie) {
            // ---- exact f64 fallback (block-uniform, rare) ----
            if (t == 0) scnt = 0;
            __syncthreads();
#pragma unroll
            for (int j = 0; j < PPT; ++j) {
                if (dist[j] >= gthf) {
                    int slot = atomicAdd(&scnt, 1);
                    if (slot < CAP) scand[slot] = t + FPS_T * j;
                }
            }
            __syncthreads();
            const int mm = scnt;
            if (mm <= CAP) {
                double bd = -1.0; int bi = INT_MAX;
#pragma unroll 1
                for (int k = 0; k < mm; ++k) {
                    const int pos = scand[k];
                    const double pxd = (double)sx[pos], pyd = (double)sy[pos],
                                 pzd = (double)sz[pos];
                    double dd = 1e10;
                    for (int i = t; i <= s; i += FPS_T) {
                        double ddx = __dsub_rn(pxd, (double)hx[i]);
                        double ddy = __dsub_rn(pyd, (double)hy[i]);
                        double ddz = __dsub_rn(pzd, (double)hz[i]);
                        double d = __dadd_rn(__dadd_rn(__dmul_rn(ddx, ddx), __dmul_rn(ddy, ddy)),
                                             __dmul_rn(ddz, ddz));
                        dd = fmin(dd, d);
                    }
#pragma unroll
                    for (int off = 32; off >= 1; off >>= 1)
                        dd = fmin(dd, __shfl_down(dd, off));
                    if (lane == 0) sdd[k & 1][w] = dd;
                    __syncthreads();
                    double ddm = sdd[k & 1][0];
#pragma unroll
                    for (int w2 = 1; w2 < NW; ++w2) ddm = fmin(ddm, sdd[k & 1][w2]);
                    if (ddm > bd || (ddm == bd && pos < bi)) { bd = ddm; bi = pos; }
                }
                i1 = bi;
            } else {
                // safety net: full exact scan (practically unreachable)
                double bv = -1.0; int bi = INT_MAX;
#pragma unroll 1
                for (int j = 0; j < PPT; ++j) {
                    const double pxd = (double)px[j], pyd = (double)py[j], pzd = (double)pz[j];
                    double dd = 1e10;
                    for (int i = 0; i <= s; ++i) {
                        double ddx = __dsub_rn(pxd, (double)hx[i]);
                        double ddy = __dsub_rn(pyd, (double)hy[i]);
                        double ddz = __dsub_rn(pzd, (double)hz[i]);
                        double d = __dadd_rn(__dadd_rn(__dmul_rn(ddx, ddx), __dmul_rn(ddy, ddy)),
                                             __dmul_rn(ddz, ddz));
                        dd = fmin(dd, d);
                    }
                    int pidx = t + FPS_T * j;
                    if (dd > bv || (dd == bv && pidx < bi)) { bv = dd; bi = pidx; }
                }
#pragma unroll
                for (int off = 32; off >= 1; off >>= 1) {
                    double ov = __shfl_down(bv, off);
                    int    oi = __shfl_down(bi, off);
                    if (ov > bv || (ov == bv && oi < bi)) { bv = ov; bi = oi; }
                }
                if (lane == 0) { sfv[w] = bv; sfo[w] = bi; }
                __syncthreads();
                bv = sfv[0]; bi = sfo[0];
#pragma unroll
                for (int w2 = 1; w2 < NW; ++w2) {
                    double ov = sfv[w2]; int oi = sfo[w2];
                    if (ov > bv || (ov == bv && oi < bi)) { bv = ov; bi = oi; }
                }
                i1 = bi;
            }
            __syncthreads();
        }
        cx = sx[i1]; cy = sy[i1]; cz = sz[i1];    // broadcast LDS reads
        buf ^= 1;
    }
    __syncthreads();
    for (int i = t; i < SCENT; i += FPS_T) {       // single coalesced-ish flush
        float* o = new_xyz + (size_t)(b * SCENT + i) * 3;
        o[0] = hx[i]; o[1] = hy[i]; o[2] = hz[i];
    }
}

// ---------------------------------------------------------------------------
// Kernel 2: transpose points (B,D,N) -> (B,N,D).
// ---------------------------------------------------------------------------
__global__ void transpose_kernel(const float* __restrict__ pts, float* __restrict__ out) {
    __shared__ float tile[32][33];
    const int b  = blockIdx.z;
    const int n0 = blockIdx.x * 32, d0 = blockIdx.y * 32;
    const int tx = threadIdx.x, ty = threadIdx.y;   // block (32,8)
#pragma unroll
    for (int i = 0; i < 4; ++i)
        tile[ty + 8 * i][tx] =
            pts[(size_t)b * DFEAT * NPTS + (size_t)(d0 + ty + 8 * i) * NPTS + n0 + tx];
    __syncthreads();
#pragma unroll
    for (int i = 0; i < 4; ++i)
        out[(size_t)b * NPTS * DFEAT + (size_t)(n0 + ty + 8 * i) * DFEAT + d0 + tx] =
            tile[tx][ty + 8 * i];
}

// ---------------------------------------------------------------------------
// Kernel 3: KNN, one WAVE per query (f64-exact ordering, wave-parallel sorted
// top-32 with ballot/shfl insertion).
// ---------------------------------------------------------------------------
__global__ __launch_bounds__(256) void knn_kernel(const float* __restrict__ xyz,
                                                  const float* __restrict__ new_xyz,
                                                  int* __restrict__ knn_idx) {
    const int b    = blockIdx.y;
    const int wid  = threadIdx.x >> 6;
    const int lane = threadIdx.x & 63;
    const int qi   = blockIdx.x * 4 + wid;

    __shared__ float4 sp[2048];
    __shared__ double sp2[2048];

    const float* q = new_xyz + (size_t)(b * SCENT + qi) * 3;
    const double qx = (double)q[0], qy = (double)q[1], qz = (double)q[2];
    const double q2 = __dadd_rn(__dadd_rn(__dmul_rn(qx, qx), __dmul_rn(qy, qy)),
                                __dmul_rn(qz, qz));

    double ld   = DBL_MAX;
    int    li   = 0x7fffffff;
    double taud = DBL_MAX;
    int    taui = 0x7fffffff;

    const float* Xb = xyz + (size_t)b * NPTS * 3;
#pragma unroll 1
    for (int c = 0; c < 4; ++c) {
        __syncthreads();
#pragma unroll
        for (int r = 0; r < 8; ++r) {
            int pl = r * 256 + threadIdx.x;
            int p  = c * 2048 + pl;
            float x = Xb[3 * p + 0], y = Xb[3 * p + 1], z = Xb[3 * p + 2];
            sp[pl] = make_float4(x, y, z, 0.0f);
            double dx = (double)x, dy = (double)y, dz = (double)z;
            sp2[pl] = __dadd_rn(__dadd_rn(__dmul_rn(dx, dx), __dmul_rn(dy, dy)),
                                __dmul_rn(dz, dz));
        }
        __syncthreads();
#pragma unroll 1
        for (int i = 0; i < 32; ++i) {
            const int pl   = i * 64 + lane;
            const int pidx = c * 2048 + pl;
            float4 P = sp[pl];
            double px = (double)P.x, py = (double)P.y, pz = (double)P.z;
            double qp = __dadd_rn(__dadd_rn(__dmul_rn(qx, px), __dmul_rn(qy, py)),
                                  __dmul_rn(qz, pz));
            double d  = __dsub_rn(__dadd_rn(q2, sp2[pl]), __dmul_rn(2.0, qp));
            bool cand = (d < taud) || (d == taud && pidx < taui);
            unsigned long long m = __ballot(cand);
            while (m) {
                int sl = __ffsll((unsigned long long)m) - 1;
                m &= m - 1;
                double dv = __shfl(d, sl);
                int    iv = __shfl(pidx, sl);
                if (dv < taud || (dv == taud && iv < taui)) {
                    bool gt = (lane < 32) && (ld > dv || (ld == dv && li > iv));
                    unsigned long long gm = __ballot(gt);
                    double ud = __shfl_up(ld, 1);
                    int    ui = __shfl_up(li, 1);
                    if (gt) { ld = ud; li = ui; }
                    bool first = gt && ((lane == 0) || !((gm >> (lane - 1)) & 1ull));
                    if (first) { ld = dv; li = iv; }
                    taud = __shfl(ld, 31);
                    taui = __shfl(li, 31);
                }
            }
        }
    }
    if (lane < 32) knn_idx[(size_t)(b * SCENT + qi) * KNEIGH + lane] = li;
}

// ---------------------------------------------------------------------------
// Kernel 4: gather + 3-layer MLP (BN folded, fp32) + max over K.
// ---------------------------------------------------------------------------
__global__ __launch_bounds__(256) void mlp_kernel(
    const float* __restrict__ xyz, const float* __restrict__ new_xyz,
    const float* __restrict__ ptsT, const int* __restrict__ knn_idx,
    const float* __restrict__ w0, const float* __restrict__ g0,
    const float* __restrict__ b0, const float* __restrict__ m0,
    const float* __restrict__ v0, const float* __restrict__ w1,
    const float* __restrict__ g1, const float* __restrict__ b1,
    const float* __restrict__ m1, const float* __restrict__ v1,
    const float* __restrict__ w2, const float* __restrict__ g2,
    const float* __restrict__ b2, const float* __restrict__ m2,
    const float* __restrict__ v2, float* __restrict__ out_points) {

    __shared__ float regA[8192];
    __shared__ float regB[4096];
    __shared__ float prm[512];

    const int t = threadIdx.x;
    if (t < 64) {
        float a0v = g0[t] / sqrtf(v0[t] + 1e-5f);
        prm[t]       = a0v;
        prm[64 + t]  = b0[t] - m0[t] * a0v;
        float a1v = g1[t] / sqrtf(v1[t] + 1e-5f);
        prm[128 + t] = a1v;
        prm[192 + t] = b1[t] - m1[t] * a1v;
    } else if (t < 192) {
        int o = t - 64;
        float a2v = g2[o] / sqrtf(v2[o] + 1e-5f);
        prm[256 + o] = a2v;
        prm[384 + o] = b2[o] - m2[o] * a2v;
    }
    for (int idx = t; idx < 64 * 68; idx += 256) {
        int o = idx / 68, i = idx - o * 68;
        float v;
        if (i < 64)      v = w0[o * 67 + 3 + i];
        else if (i < 67) v = w0[o * 67 + (i - 64)];
        else             v = 0.0f;
        regA[idx] = v;
    }
    for (int idx = t; idx < 64 * 64; idx += 256) regB[idx] = w1[idx];
    __syncthreads();

    const int gid = blockIdx.x * 256 + t;
    const int sl  = gid >> 5;
    const int s   = sl & (SCENT - 1);
    const int b   = sl >> 11;
    const int nidx = knn_idx[gid];

    const float* q  = new_xyz + (size_t)(b * SCENT + s) * 3;
    const float* P3 = xyz + (size_t)(b * NPTS + nidx) * 3;
    const float dx = P3[0] - q[0], dy = P3[1] - q[1], dz = P3[2] - q[2];

    const float4* F = (const float4*)(ptsT + ((size_t)b * NPTS + nidx) * 64);
    float4 xv[17];
#pragma unroll
    for (int i = 0; i < 16; ++i) xv[i] = F[i];
    xv[16] = make_float4(dx, dy, dz, 0.0f);

    float h0[64];
    const float4* W0 = (const float4*)regA;
#pragma unroll
    for (int o = 0; o < 64; ++o) {
        float acc = 0.f;
#pragma unroll
        for (int i = 0; i < 17; ++i) {
            float4 w = W0[o * 17 + i];
            acc = fmaf(xv[i].x, w.x, acc);
            acc = fmaf(xv[i].y, w.y, acc);
            acc = fmaf(xv[i].z, w.z, acc);
            acc = fmaf(xv[i].w, w.w, acc);
        }
        h0[o] = fmaxf(fmaf(acc, prm[o], prm[64 + o]), 0.f);
    }
    __syncthreads();
    for (int idx = t; idx < 128 * 64; idx += 256) regA[idx] = w2[idx];
    __syncthreads();

    float h1[64];
    const float4* W1 = (const float4*)regB;
#pragma unroll
    for (int o = 0; o < 64; ++o) {
        float acc = 0.f;
#pragma unroll
        for (int i = 0; i < 16; ++i) {
            float4 w = W1[o * 16 + i];
            acc = fmaf(h0[4 * i + 0], w.x, acc);
            acc = fmaf(h0[4 * i + 1], w.y, acc);
            acc = fmaf(h0[4 * i + 2], w.z, acc);
            acc = fmaf(h0[4 * i + 3], w.w, acc);
        }
        h1[o] = fmaxf(fmaf(acc, prm[128 + o], prm[192 + o]), 0.f);
    }

    const float4* W2 = (const float4*)regA;
    float* outp = out_points + (size_t)b * 128 * SCENT + s;
    const int lane = t & 63;
#pragma unroll 1
    for (int o = 0; o < 128; ++o) {
        float acc = 0.f;
#pragma unroll
        for (int i = 0; i < 16; ++i) {
            float4 w = W2[o * 16 + i];
            acc = fmaf(h1[4 * i + 0], w.x, acc);
            acc = fmaf(h1[4 * i + 1], w.y, acc);
            acc = fmaf(h1[4 * i + 2], w.z, acc);
            acc = fmaf(h1[4 * i + 3], w.w, acc);
        }
        float y = fmaxf(fmaf(acc, prm[256 + o], prm[384 + o]), 0.f);
#pragma unroll
        for (int off = 16; off >= 1; off >>= 1) y = fmaxf(y, __shfl_xor(y, off));
        if ((lane & 31) == 0) outp[(size_t)o * SCENT] = y;
    }
}

// ---------------------------------------------------------------------------
extern "C" void kernel_launch(void* const* d_in, const int* in_sizes, int n_in,
                              void* d_out, int out_size, void* d_ws, size_t ws_size,
                              hipStream_t stream) {
    const float* xyz    = (const float*)d_in[0];
    const float* points = (const float*)d_in[1];
    const float* w0 = (const float*)d_in[2];
    const float* g0 = (const float*)d_in[3];
    const float* b0 = (const float*)d_in[4];
    const float* m0 = (const float*)d_in[5];
    const float* v0 = (const float*)d_in[6];
    const float* w1 = (const float*)d_in[7];
    const float* g1 = (const float*)d_in[8];
    const float* b1 = (const float*)d_in[9];
    const float* m1 = (const float*)d_in[10];
    const float* v1 = (const float*)d_in[11];
    const float* w2 = (const float*)d_in[12];
    const float* g2 = (const float*)d_in[13];
    const float* b2 = (const float*)d_in[14];
    const float* m2 = (const float*)d_in[15];
    const float* v2 = (const float*)d_in[16];

    float* out_xyz    = (float*)d_out;                               // (B,S,3)
    float* out_points = (float*)d_out + (size_t)BATCH * SCENT * 3;   // (B,128,S)

    char* ws = (char*)d_ws;
    int*   knn_idx = (int*)(ws + 32768);
    float* ptsT    = (float*)(ws + 32768 + (size_t)BATCH * SCENT * KNEIGH * 4);

    fps_kernel<<<BATCH, FPS_T, 0, stream>>>(xyz, out_xyz);
    transpose_kernel<<<dim3(NPTS / 32, DFEAT / 32, BATCH), dim3(32, 8), 0, stream>>>(points, ptsT);
    knn_kernel<<<dim3(SCENT / 4, BATCH), 256, 0, stream>>>(xyz, out_xyz, knn_idx);
    mlp_kernel<<<(BATCH * SCENT * KNEIGH) / 256, 256, 0, stream>>>(
        xyz, out_xyz, ptsT, knn_idx,
        w0, g0, b0, m0, v0, w1, g1, b1, m1, v1, w2, g2, b2, m2, v2, out_points);
}